// Round 11
// baseline (38.263 us; speedup 1.0000x reference)
//
#include <hip/hip_runtime.h>

#define S_LEN  64000
#define B_N    64
#define MCH    8            // steps per micro-chunk (one lane-group's serial chain)
#define CPB    16           // micro-chunks per block (2 per wave)
#define BSTEPS (MCH * CPB)  // 128 steps per macro block
#define NMAC   (S_LEN / BSTEPS)  // 500 macro chunks
#define RSTEPS 64               // steps per replay block
#define NREP   (S_LEN / RSTEPS) // 1000 replay blocks
#define RWPB   8                // waves per replay block
#define SC_T   1024         // scan threads (>= NMAC)

struct Aff { float m00, m01, m10, m11, v0, v1; };

__device__ __forceinline__ Aff aff_id() {
    Aff r; r.m00 = 1.f; r.m01 = 0.f; r.m10 = 0.f; r.m11 = 1.f; r.v0 = 0.f; r.v1 = 0.f;
    return r;
}

// X ∘ Y : apply Y first, then X
__device__ __forceinline__ Aff aff_comp(const Aff& X, const Aff& Y) {
    Aff r;
    r.m00 = fmaf(X.m00, Y.m00, X.m01 * Y.m10);
    r.m01 = fmaf(X.m00, Y.m01, X.m01 * Y.m11);
    r.m10 = fmaf(X.m10, Y.m00, X.m11 * Y.m10);
    r.m11 = fmaf(X.m10, Y.m01, X.m11 * Y.m11);
    r.v0  = fmaf(X.m00, Y.v0, fmaf(X.m01, Y.v1, X.v0));
    r.v1  = fmaf(X.m10, Y.v0, fmaf(X.m11, Y.v1, X.v1));
    return r;
}

// Per-step transform: state' = A*state + c, A = 2H - I, c = 2*gHBx
__device__ __forceinline__ Aff svf_step(float g, float R, float x) {
    Aff a;
    float T  = 1.0f / fmaf(g, g + R, 1.0f);
    float gT = g * T;
    a.m00 = fmaf(2.0f, T, -1.0f);
    a.m01 = -2.0f * gT;
    a.m10 =  2.0f * gT;
    a.m11 = fmaf(2.0f, fmaf(R, gT, T), -1.0f);
    a.v0  = a.m10 * x;
    a.v1  = g * a.v0;
    return a;
}

// LDS staging, stride 7 floats -> 2 lanes/bank max (free)
__device__ __forceinline__ void aff_store_lds(float* p, const Aff& a) {
    p[0] = a.m00; p[1] = a.m01; p[2] = a.m10; p[3] = a.m11; p[4] = a.v0; p[5] = a.v1;
}
__device__ __forceinline__ Aff aff_load_lds(const float* p) {
    Aff a; a.m00 = p[0]; a.m01 = p[1]; a.m10 = p[2]; a.m11 = p[3]; a.v0 = p[4]; a.v1 = p[5];
    return a;
}
// Packed global Aff: 2 x float4 (32 B)
__device__ __forceinline__ void aff_store_g4(float4* p, const Aff& a) {
    p[0] = make_float4(a.m00, a.m01, a.m10, a.m11);
    p[1] = make_float4(a.v0,  a.v1,  0.f,   0.f);
}
__device__ __forceinline__ Aff aff_load_g4(const float4* p) {
    float4 x = p[0], y = p[1];
    Aff a; a.m00 = x.x; a.m01 = x.y; a.m10 = x.z; a.m11 = x.w; a.v0 = y.x; a.v1 = y.y;
    return a;
}

// Pass 1: lane (half h = lane>>5, pair j = lane&31) composes the 8-step
// micro transform of chunk c = 2w+h for batches (2j, 2j+1) using float2
// loads (8 B/lane, 512 B per wave-instruction). Block composes its 16
// micros (128 steps) into a macro M and snapshots the half-macro H
// (first 64 steps). Layouts [batch][macro] for coalesced scan reads.
__global__ __launch_bounds__(512, 4) void k_macro(
    const float* __restrict__ audio, const float* __restrict__ g,
    const float* __restrict__ twoR, float4* __restrict__ wsMac,
    float4* __restrict__ wsHalf)
{
    __shared__ float affs[CPB * B_N * 7];   // 28.7 KB
    const int lane = threadIdx.x & 63;
    const int w    = threadIdx.x >> 6;
    const int j2   = lane & 31;             // batch pair -> batches 2j2, 2j2+1
    const int h    = lane >> 5;
    const int c    = w * 2 + h;             // micro-chunk 0..15
    const int blk  = blockIdx.x;
    const int base = (blk * BSTEPS + c * MCH) * B_N + 2 * j2;

    Aff accA = aff_id(), accB = aff_id();
#pragma unroll
    for (int i = 0; i < MCH; ++i) {
        const int idx = base + i * B_N;
        float2 gg = *(const float2*)&g[idx];
        float2 RR = *(const float2*)&twoR[idx];
        float2 xx = *(const float2*)&audio[idx];
        accA = aff_comp(svf_step(gg.x, RR.x, xx.x), accA);
        accB = aff_comp(svf_step(gg.y, RR.y, xx.y), accB);
    }
    aff_store_lds(&affs[(c * B_N + 2 * j2)     * 7], accA);
    aff_store_lds(&affs[(c * B_N + 2 * j2 + 1) * 7], accB);
    __syncthreads();

    if (w == 0) {                           // 64 lanes = 64 batches
        const int b = lane;
        Aff M = aff_load_lds(&affs[b * 7]); // chunk 0
        Aff H = M;
#pragma unroll
        for (int j = 1; j < CPB; ++j) {
            M = aff_comp(aff_load_lds(&affs[(j * B_N + b) * 7]), M);
            if (j == CPB / 2 - 1) H = M;    // product of chunks 0..7 (64 steps)
        }
        aff_store_g4(&wsHalf[((long)b * NMAC + blk) * 2], H);
        aff_store_g4(&wsMac [((long)b * NMAC + blk) * 2], M);
    }
}

// Pass 2: one block (1024 threads) per batch; thread t owns macro t (<500).
// Contiguous 32 B loads. Wave-inclusive shuffle scan -> wave 0 scans wave
// totals -> exclusive prefix E_t -> emit TWO 64-step entry states per
// macro: sIn[2t] = E_t(s0), sIn[2t+1] = (H_t ∘ E_t)(s0).
__global__ __launch_bounds__(SC_T, 2) void k_scan(
    const float4* __restrict__ wsMac, const float4* __restrict__ wsHalf,
    float2* __restrict__ sIn)
{
    const int b    = blockIdx.x;   // batch
    const int t    = threadIdx.x;  // macro index
    const int lane = t & 63;
    const int wave = t >> 6;       // 0..15

    Aff m = (t < NMAC) ? aff_load_g4(&wsMac[((long)b * NMAC + t) * 2]) : aff_id();

    // wave-inclusive Hillis-Steele scan
    Aff acc = m;
#pragma unroll
    for (int d = 1; d < 64; d <<= 1) {
        Aff o;
        o.m00 = __shfl_up(acc.m00, (unsigned)d, 64);
        o.m01 = __shfl_up(acc.m01, (unsigned)d, 64);
        o.m10 = __shfl_up(acc.m10, (unsigned)d, 64);
        o.m11 = __shfl_up(acc.m11, (unsigned)d, 64);
        o.v0  = __shfl_up(acc.v0,  (unsigned)d, 64);
        o.v1  = __shfl_up(acc.v1,  (unsigned)d, 64);
        if (lane >= d) acc = aff_comp(acc, o);
    }

    __shared__ Aff wt[SC_T / 64];
    if (lane == 63) wt[wave] = acc;
    __syncthreads();

    // wave 0: inclusive scan of the 16 wave totals (lanes 0..15)
    if (wave == 0 && lane < 16) {
        Aff a = wt[lane];
#pragma unroll
        for (int d = 1; d < 16; d <<= 1) {
            Aff o;
            o.m00 = __shfl_up(a.m00, (unsigned)d, 64);
            o.m01 = __shfl_up(a.m01, (unsigned)d, 64);
            o.m10 = __shfl_up(a.m10, (unsigned)d, 64);
            o.m11 = __shfl_up(a.m11, (unsigned)d, 64);
            o.v0  = __shfl_up(a.v0,  (unsigned)d, 64);
            o.v1  = __shfl_up(a.v1,  (unsigned)d, 64);
            if (lane >= d) a = aff_comp(a, o);
        }
        wt[lane] = a;
    }
    __syncthreads();

    if (t < NMAC) {
        // exclusive within wave
        Aff E;
        E.m00 = __shfl_up(acc.m00, 1u, 64);
        E.m01 = __shfl_up(acc.m01, 1u, 64);
        E.m10 = __shfl_up(acc.m10, 1u, 64);
        E.m11 = __shfl_up(acc.m11, 1u, 64);
        E.v0  = __shfl_up(acc.v0,  1u, 64);
        E.v1  = __shfl_up(acc.v1,  1u, 64);
        if (lane == 0) E = aff_id();
        if (wave > 0) E = aff_comp(E, wt[wave - 1]);

        // entry state of replay block 2t: E applied to s0 = (1,1)
        sIn[(2 * t) * B_N + b] =
            make_float2(E.m00 + E.m01 + E.v0, E.m10 + E.m11 + E.v1);

        // entry state of replay block 2t+1: (H ∘ E) applied to s0
        Aff H  = aff_load_g4(&wsHalf[((long)b * NMAC + t) * 2]);
        Aff HE = aff_comp(H, E);
        sIn[(2 * t + 1) * B_N + b] =
            make_float2(HE.m00 + HE.m01 + HE.v0, HE.m10 + HE.m11 + HE.v1);
    }
}

// Pass 3 (unchanged from R10): wave w recomputes its micro transform,
// block shares micros via LDS, wave composes its within-block prefix ->
// exact entry state, replays 8 steps. Transposed 256 B-coalesced stores.
__global__ __launch_bounds__(512, 4) void k_replay(
    const float* __restrict__ audio, const float* __restrict__ g,
    const float* __restrict__ twoR, const float* __restrict__ mix,
    const float2* __restrict__ sIn, float* __restrict__ out)
{
    __shared__ float lds[RSTEPS * 65];  // reused: first RWPB*64*7 = Aff staging
    const int b   = threadIdx.x & 63;
    const int w   = threadIdx.x >> 6;
    const int blk = blockIdx.x;
    const int base = (blk * RSTEPS + w * MCH) * B_N + b;

    const float3* mix3 = (const float3*)mix;
    float gv[MCH], Rv[MCH], xv[MCH];
    float3 mv[MCH];
#pragma unroll
    for (int i = 0; i < MCH; ++i) {
        const int idx = base + i * B_N;
        gv[i] = g[idx]; Rv[i] = twoR[idx]; xv[i] = audio[idx];
        mv[i] = mix3[idx];
    }

    Aff acc = aff_id();
#pragma unroll
    for (int i = 0; i < MCH; ++i)
        acc = aff_comp(svf_step(gv[i], Rv[i], xv[i]), acc);
    aff_store_lds(&lds[(w * B_N + b) * 7], acc);
    __syncthreads();

    float2 sm = sIn[blk * B_N + b];
    Aff P = aff_id();
    for (int j = 0; j < w; ++j) {
        Aff A = aff_load_lds(&lds[(j * B_N + b) * 7]);
        P = aff_comp(A, P);
    }
    float s0 = fmaf(P.m00, sm.x, fmaf(P.m01, sm.y, P.v0));
    float s1 = fmaf(P.m10, sm.x, fmaf(P.m11, sm.y, P.v1));
    __syncthreads();

#pragma unroll
    for (int i = 0; i < MCH; ++i) {
        float gg = gv[i], R = Rv[i], x = xv[i];
        float T  = 1.0f / fmaf(gg, gg + R, 1.0f);
        float gT = gg * T;
        float b0 = gT * x;
        float b1 = gg * b0;
        float Y0 = fmaf(T, s0, fmaf(-gT, s1, b0));
        float Y1 = fmaf(gT, s0, fmaf(fmaf(R, gT, T), s1, b1));
        s0 = fmaf(2.0f, Y0, -s0);
        s1 = fmaf(2.0f, Y1, -s1);

        float yh = x - fmaf(R, Y0, Y1);
        float y  = fmaf(R * mv[i].x, Y0, fmaf(mv[i].y, Y1, mv[i].z * yh));

        lds[(w * MCH + i) * 65 + b] = y;
    }
    __syncthreads();

    const int col = threadIdx.x & 63;
    const int r0  = threadIdx.x >> 6;
    const int colbase = blk * RSTEPS;
#pragma unroll
    for (int r = r0; r < B_N; r += RWPB) {
        out[r * S_LEN + colbase + col] = lds[col * 65 + r];
    }
}

extern "C" void kernel_launch(void* const* d_in, const int* in_sizes, int n_in,
                              void* d_out, int out_size, void* d_ws, size_t ws_size,
                              hipStream_t stream)
{
    const float* audio = (const float*)d_in[0];
    const float* g     = (const float*)d_in[1];
    const float* twoR  = (const float*)d_in[2];
    const float* mix   = (const float*)d_in[3];
    float* out = (float*)d_out;

    float4* wsMac  = (float4*)d_ws;                        // 64*NMAC*2 float4 (1 MB)
    float4* wsHalf = wsMac + (long)B_N * NMAC * 2;         // 64*NMAC*2 float4 (1 MB)
    float2* sIn    = (float2*)(wsHalf + (long)B_N * NMAC * 2); // NREP*64 float2 (0.5 MB)

    k_macro <<<dim3(NMAC), dim3(512), 0, stream>>>(audio, g, twoR, wsMac, wsHalf);
    k_scan  <<<dim3(B_N), dim3(SC_T), 0, stream>>>(wsMac, wsHalf, sIn);
    k_replay<<<dim3(NREP), dim3(512), 0, stream>>>(audio, g, twoR, mix, sIn, out);
}